// Round 3
// baseline (19570.450 us; speedup 1.0000x reference)
//
#include <hip/hip_runtime.h>

#define N_ROWS  1048576      // B*L = 2048*512
#define NSTEPS  64
#define DT      0.0625f      // 4/64
#define BLOCK   256

// ---------- compile-time threefry for the 64 per-step folded keys ----------
// fold_in(key(42), i) = threefry_2x32(key=(0,42), count=[0,i]) -> (x0f, x1f)
// (legacy threefry_2x32 path; NOT affected by jax_threefry_partitionable)
constexpr unsigned rotl_c(unsigned x, int r) { return (x << r) | (x >> (32 - r)); }

struct KeyTab { unsigned a[NSTEPS]; unsigned b[NSTEPS]; };

constexpr KeyTab make_keytab() {
  KeyTab t{};
  for (int i = 0; i < NSTEPS; ++i) {
    const int R0[4] = {13, 15, 26, 6};
    const int R1[4] = {17, 29, 16, 24};
    unsigned k1 = 0u, k2 = 42u;
    unsigned ks[3] = {k1, k2, k1 ^ k2 ^ 0x1BD11BDAu};
    unsigned x0 = 0u + ks[0];
    unsigned x1 = (unsigned)i + ks[1];
    for (int g = 0; g < 5; ++g) {
      const int* R = (g % 2 == 0) ? R0 : R1;
      for (int q = 0; q < 4; ++q) { x0 += x1; x1 = rotl_c(x1, R[q]); x1 ^= x0; }
      x0 += ks[(g + 1) % 3];
      x1 += ks[(g + 2) % 3] + (unsigned)(g + 1);
    }
    t.a[i] = x0; t.b[i] = x1;
  }
  return t;
}

__constant__ KeyTab KEYTAB = make_keytab();

// ---------- device threefry2x32 (20 rounds, JAX schedule) ----------
// Partitionable random_bits, 32-bit dtype: element n gets
//   bits = x0_final ^ x1_final   of threefry(key, c0=hi32(n)=0, c1=lo32(n)=n)
// (jax/_src/prng.py::_threefry_random_bits_partitionable: bits1 ^ bits2)
#define TF_ROUND(x0, x1, r) { x0 += x1; x1 = (x1 << (r)) | (x1 >> (32 - (r))); x1 ^= x0; }

__device__ __forceinline__ unsigned threefry_xor(unsigned k1, unsigned k2, unsigned c1) {
  unsigned ks2 = k1 ^ k2 ^ 0x1BD11BDAu;
  unsigned x0 = k1;          // c0 = 0
  unsigned x1 = c1 + k2;
  TF_ROUND(x0, x1, 13) TF_ROUND(x0, x1, 15) TF_ROUND(x0, x1, 26) TF_ROUND(x0, x1, 6)
  x0 += k2;  x1 += ks2 + 1u;
  TF_ROUND(x0, x1, 17) TF_ROUND(x0, x1, 29) TF_ROUND(x0, x1, 16) TF_ROUND(x0, x1, 24)
  x0 += ks2; x1 += k1 + 2u;
  TF_ROUND(x0, x1, 13) TF_ROUND(x0, x1, 15) TF_ROUND(x0, x1, 26) TF_ROUND(x0, x1, 6)
  x0 += k1;  x1 += k2 + 3u;
  TF_ROUND(x0, x1, 17) TF_ROUND(x0, x1, 29) TF_ROUND(x0, x1, 16) TF_ROUND(x0, x1, 24)
  x0 += k2;  x1 += ks2 + 4u;
  TF_ROUND(x0, x1, 13) TF_ROUND(x0, x1, 15) TF_ROUND(x0, x1, 26) TF_ROUND(x0, x1, 6)
  x0 += ks2; x1 += k1 + 5u;
  return x0 ^ x1;
}

// ---------- bits -> N(0,1), replicating JAX uniform + XLA ErfInv32 ----------
__device__ __forceinline__ float gauss_from_bits(unsigned bits) {
  const float lo = -0x1.fffffep-1f;  // nextafter(-1, 0)
  float f = __uint_as_float((bits >> 9) | 0x3f800000u) - 1.0f;  // [0,1)
  float u = fmaf(f, 2.0f, lo);   // (maxval-minval) rounds to exactly 2.0f
  u = fmaxf(u, lo);
  float w = -log1pf(-u * u);
  float p;
  if (w < 5.0f) {
    w -= 2.5f;
    p = 2.81022636e-08f;
    p = fmaf(p, w, 3.43273939e-07f);
    p = fmaf(p, w, -3.5233877e-06f);
    p = fmaf(p, w, -4.39150654e-06f);
    p = fmaf(p, w, 0.00021858087f);
    p = fmaf(p, w, -0.00125372503f);
    p = fmaf(p, w, -0.00417768164f);
    p = fmaf(p, w, 0.246640727f);
    p = fmaf(p, w, 1.50140941f);
  } else {
    w = sqrtf(w) - 3.0f;
    p = -0.000200214257f;
    p = fmaf(p, w, 0.000100950558f);
    p = fmaf(p, w, 0.00134934322f);
    p = fmaf(p, w, -0.00367342844f);
    p = fmaf(p, w, 0.00573950773f);
    p = fmaf(p, w, -0.0076224613f);
    p = fmaf(p, w, 0.00943887047f);
    p = fmaf(p, w, 1.00167406f);
    p = fmaf(p, w, 2.83297682f);
  }
  return 1.41421356237f * p * u;
}

__device__ __forceinline__ float softplusf(float v) {
  return fmaxf(v, 0.f) + log1pf(expf(-fabsf(v)));
}

// ---------- fused SDE-net forward; one thread = one row ----------
__global__ void __launch_bounds__(BLOCK) sde_fused(
    const float* __restrict__ x,
    const float* __restrict__ Wdown,  const float* __restrict__ bdown,
    const float* __restrict__ Wdrift, const float* __restrict__ bdrift,
    const float* __restrict__ Wd1,    const float* __restrict__ bd1,
    const float* __restrict__ Wd2,    const float* __restrict__ bd2,
    const float* __restrict__ Wfc,    const float* __restrict__ bfc,
    float* __restrict__ out) {
  // o-state in LDS: stride 51 -> lane-to-bank stride 19 (coprime with 32),
  // 64 lanes -> 2 lanes/bank = free. 256 thr * 51 * 4B = 52.2 KB.
  __shared__ float smem[BLOCK * 51];
  const int tid = threadIdx.x;
  const int r   = blockIdx.x * BLOCK + tid;   // row in [0, N_ROWS)
  float* __restrict__ o = &smem[tid * 51];

  // ---- down-projection: o = x @ W_down + b_down ----
  {
    const float4* xp = (const float4*)(x + (size_t)r * 24);  // 96B rows, 16B aligned
    float xr[24];
#pragma unroll
    for (int q = 0; q < 6; ++q) {
      float4 v = xp[q];
      xr[q * 4 + 0] = v.x; xr[q * 4 + 1] = v.y; xr[q * 4 + 2] = v.z; xr[q * 4 + 3] = v.w;
    }
    for (int f = 0; f < 50; ++f) {
      float acc = bdown[f];
#pragma unroll
      for (int k = 0; k < 24; ++k) acc = fmaf(xr[k], Wdown[k * 50 + f], acc);
      o[f] = acc;
    }
  }

  // ---- diffusion coefficient at t=0: coef = 5*sigmoid(h)*0.25 ----
  float coef;
  {
    float va[50];
#pragma unroll
    for (int f = 0; f < 50; ++f) va[f] = o[f];
    float h = bd2[0];
    for (int m = 0; m < 100; ++m) {
      float a = bd1[m];
#pragma unroll
      for (int k = 0; k < 50; ++k) a = fmaf(va[k], Wd1[k * 100 + m], a);
      h = fmaf(fmaxf(a, 0.f), Wd2[m], h);
    }
    coef = 1.25f / (1.f + expf(-h));
  }

  // ---- 64 Euler-Maruyama steps ----
  const unsigned nbase = (unsigned)r * 50u;   // flat noise index base (< 2^32)
  for (int s = 0; s < NSTEPS; ++s) {
    const unsigned k1 = KEYTAB.a[s];
    const unsigned k2 = KEYTAB.b[s];

    float tmp[50];
#pragma unroll
    for (int j = 0; j < 50; ++j) tmp[j] = bdrift[j];
    for (int k = 0; k < 50; ++k) {
      float a = o[k];
#pragma unroll
      for (int j = 0; j < 50; ++j) tmp[j] = fmaf(a, Wdrift[k * 50 + j], tmp[j]);
    }
#pragma unroll
    for (int j = 0; j < 50; ++j) o[j] += fmaxf(tmp[j], 0.f) * DT;

#pragma unroll 2
    for (int f = 0; f < 50; ++f) {
      unsigned bits = threefry_xor(k1, k2, nbase + (unsigned)f);
      o[f] += coef * gauss_from_bits(bits);
    }
  }

  // ---- head ----
  {
    float mu = bfc[0], sv = bfc[1];
    for (int f = 0; f < 50; ++f) {
      float rv = fmaxf(o[f], 0.f);
      mu = fmaf(rv, Wfc[f * 2 + 0], mu);
      sv = fmaf(rv, Wfc[f * 2 + 1], sv);
    }
    out[r]          = mu;
    out[N_ROWS + r] = softplusf(sv) + 0.001f;
  }
}

extern "C" void kernel_launch(void* const* d_in, const int* in_sizes, int n_in,
                              void* d_out, int out_size, void* d_ws, size_t ws_size,
                              hipStream_t stream) {
  const float* x      = (const float*)d_in[0];
  const float* Wdown  = (const float*)d_in[1];
  const float* bdown  = (const float*)d_in[2];
  const float* Wdrift = (const float*)d_in[3];
  const float* bdrift = (const float*)d_in[4];
  const float* Wd1    = (const float*)d_in[5];
  const float* bd1    = (const float*)d_in[6];
  const float* Wd2    = (const float*)d_in[7];
  const float* bd2    = (const float*)d_in[8];
  const float* Wfc    = (const float*)d_in[9];
  const float* bfc    = (const float*)d_in[10];
  float* out = (float*)d_out;

  dim3 grid(N_ROWS / BLOCK), block(BLOCK);
  hipLaunchKernelGGL(sde_fused, grid, block, 0, stream,
                     x, Wdown, bdown, Wdrift, bdrift, Wd1, bd1, Wd2, bd2, Wfc, bfc, out);
}

// Round 5
// 11225.066 us; speedup vs baseline: 1.7435x; 1.7435x over previous
//
#include <hip/hip_runtime.h>
#include <hip/hip_bf16.h>

#define N_ROWS  1048576      // B*L = 2048*512
#define NSTEPS  64
#define DT      0.0625f      // 4/64
#define BLOCK   256          // 4 waves; each wave owns 16 rows
#define WPB     4
#define RPW     16
#define SROW    68           // stage row stride in floats (64 + 4 pad)

typedef __attribute__((ext_vector_type(8))) short bfrag8;   // 8 bf16 (4 VGPRs)
typedef __attribute__((ext_vector_type(4))) float f32x4;    // MFMA C/D

union FragU { bfrag8 v; unsigned u[4]; };

// ---------- compile-time threefry for the 64 per-step folded keys ----------
constexpr unsigned rotl_c(unsigned x, int r) { return (x << r) | (x >> (32 - r)); }
struct KeyTab { unsigned a[NSTEPS]; unsigned b[NSTEPS]; };
constexpr KeyTab make_keytab() {
  KeyTab t{};
  for (int i = 0; i < NSTEPS; ++i) {
    const int R0[4] = {13, 15, 26, 6};
    const int R1[4] = {17, 29, 16, 24};
    unsigned k1 = 0u, k2 = 42u;
    unsigned ks[3] = {k1, k2, k1 ^ k2 ^ 0x1BD11BDAu};
    unsigned x0 = 0u + ks[0];
    unsigned x1 = (unsigned)i + ks[1];
    for (int g = 0; g < 5; ++g) {
      const int* R = (g % 2 == 0) ? R0 : R1;
      for (int qq = 0; qq < 4; ++qq) { x0 += x1; x1 = rotl_c(x1, R[qq]); x1 ^= x0; }
      x0 += ks[(g + 1) % 3];
      x1 += ks[(g + 2) % 3] + (unsigned)(g + 1);
    }
    t.a[i] = x0; t.b[i] = x1;
  }
  return t;
}
__constant__ KeyTab KEYTAB = make_keytab();

// ---------- device threefry2x32 (EXACT, bit-verified in R3) ----------
#define TF_ROUND(x0, x1, r) { x0 += x1; x1 = (x1 << (r)) | (x1 >> (32 - (r))); x1 ^= x0; }
__device__ __forceinline__ unsigned threefry_xor(unsigned k1, unsigned k2, unsigned c1) {
  unsigned ks2 = k1 ^ k2 ^ 0x1BD11BDAu;
  unsigned x0 = k1;          // c0 = 0
  unsigned x1 = c1 + k2;
  TF_ROUND(x0, x1, 13) TF_ROUND(x0, x1, 15) TF_ROUND(x0, x1, 26) TF_ROUND(x0, x1, 6)
  x0 += k2;  x1 += ks2 + 1u;
  TF_ROUND(x0, x1, 17) TF_ROUND(x0, x1, 29) TF_ROUND(x0, x1, 16) TF_ROUND(x0, x1, 24)
  x0 += ks2; x1 += k1 + 2u;
  TF_ROUND(x0, x1, 13) TF_ROUND(x0, x1, 15) TF_ROUND(x0, x1, 26) TF_ROUND(x0, x1, 6)
  x0 += k1;  x1 += k2 + 3u;
  TF_ROUND(x0, x1, 17) TF_ROUND(x0, x1, 29) TF_ROUND(x0, x1, 16) TF_ROUND(x0, x1, 24)
  x0 += k2;  x1 += ks2 + 4u;
  TF_ROUND(x0, x1, 13) TF_ROUND(x0, x1, 15) TF_ROUND(x0, x1, 26) TF_ROUND(x0, x1, 6)
  x0 += ks2; x1 += k1 + 5u;
  return x0 ^ x1;
}

// ---------- bits -> N(0,1): exact uniform map, fast log, branchless erfinv ----------
// coefficients pre-multiplied by sqrt(2); w via v_log_f32 (rel err ~1e-7, OK vs 10x slack)
__device__ __forceinline__ float gauss_from_bits(unsigned bits) {
  float f = __uint_as_float((bits >> 9) | 0x3f800000u) - 1.0f;
  float u = fmaf(f, 2.0f, -0x1.fffffep-1f);   // [-0.99999994, 1)
  float w = -__logf(fmaf(-u, u, 1.0f));       // -ln(1 - u^2), arg >= 1.2e-7
  float wm = w - 2.5f;
  float p1 = 3.97402802e-08f;
  p1 = fmaf(p1, wm, 4.85466e-07f);
  p1 = fmaf(p1, wm, -4.98282e-06f);
  p1 = fmaf(p1, wm, -6.21053e-06f);
  p1 = fmaf(p1, wm, 3.09122e-04f);
  p1 = fmaf(p1, wm, -1.77303338e-03f);
  p1 = fmaf(p1, wm, -5.90813529e-03f);
  p1 = fmaf(p1, wm, 3.48803145e-01f);
  p1 = fmaf(p1, wm, 2.12331534e+00f);
  float ws = __builtin_amdgcn_sqrtf(w) - 3.0f;
  float p2 = -2.83146976e-04f;
  p2 = fmaf(p2, ws, 1.42765612e-04f);
  p2 = fmaf(p2, ws, 1.90826526e-03f);
  p2 = fmaf(p2, ws, -5.19504700e-03f);
  p2 = fmaf(p2, ws, 8.11689600e-03f);
  p2 = fmaf(p2, ws, -1.07798700e-02f);
  p2 = fmaf(p2, ws, 1.33487100e-02f);
  p2 = fmaf(p2, ws, 1.41658100e+00f);
  p2 = fmaf(p2, ws, 4.00643426e+00f);
  float p = (w < 5.0f) ? p1 : p2;
  return p * u;                                // = sqrt(2)*erfinv(u)
}

__device__ __forceinline__ float softplusf(float v) {
  return fmaxf(v, 0.f) + log1pf(expf(-fabsf(v)));
}

__device__ __forceinline__ unsigned packbf(float lo, float hi) {
  __hip_bfloat162 h = __float22bfloat162_rn(make_float2(lo, hi));  // .x = low half
  unsigned r; __builtin_memcpy(&r, &h, 4); return r;
}

// ---------- fused SDE-net forward; one wave = 16 rows, MFMA drift ----------
__global__ void __launch_bounds__(BLOCK, 4) sde_fused(
    const float* __restrict__ x,
    const float* __restrict__ Wdown,  const float* __restrict__ bdown,
    const float* __restrict__ Wdrift, const float* __restrict__ bdrift,
    const float* __restrict__ Wd1,    const float* __restrict__ bd1,
    const float* __restrict__ Wd2,    const float* __restrict__ bd2,
    const float* __restrict__ Wfc,    const float* __restrict__ bfc,
    float* __restrict__ out) {
  // wave-private f32 staging: o[16 rows][64 feats], stride 68 -> <=2-way banks
  __shared__ __align__(16) float stage[WPB][RPW][SROW];
  __shared__ float coefs[WPB][RPW];

  const int tid  = threadIdx.x;
  const int wave = tid >> 6;
  const int lane = tid & 63;
  const int q    = lane >> 4;       // quad 0..3
  const int c    = lane & 15;       // col-in-tile / A-row
  const int wbase = (blockIdx.x * WPB + wave) * RPW;

  // ---- loop-invariant B-fragments of W_drift (padded 64x64, bf16) ----
  // B[k][n]: lane holds k = h*32 + q*8 + j (j=0..7), n = t*16 + c
  FragU Bf[4][2];
#pragma unroll
  for (int t = 0; t < 4; ++t) {
    const int nn = t * 16 + c;
    const bool nv = nn < 50;
#pragma unroll
    for (int h = 0; h < 2; ++h) {
#pragma unroll
      for (int j2 = 0; j2 < 4; ++j2) {
        const int k0 = h * 32 + q * 8 + j2 * 2;
        float v0 = (nv && k0 < 50)     ? Wdrift[k0 * 50 + nn]       : 0.f;
        float v1 = (nv && (k0+1) < 50) ? Wdrift[(k0 + 1) * 50 + nn] : 0.f;
        Bf[t][h].u[j2] = packbf(v0, v1);
      }
    }
  }
  // C-init = b_drift broadcast per tile (0 on pad cols)
  f32x4 Cb[4];
#pragma unroll
  for (int t = 0; t < 4; ++t) {
    const int nn = t * 16 + c;
    float b = (nn < 50) ? bdrift[nn] : 0.f;
    Cb[t] = (f32x4){b, b, b, b};
  }

  // ---- down-projection into master registers (D-layout) + stage ----
  float o_m[4][4];   // o_m[t][g]: row = 4q+g, feat = t*16+c
#pragma unroll
  for (int g = 0; g < 4; ++g) {
    const float* xrp = x + (size_t)(wbase + 4 * q + g) * 24;
    float xr[24];
#pragma unroll
    for (int i = 0; i < 6; ++i) {
      float4 v = ((const float4*)xrp)[i];
      xr[i*4+0] = v.x; xr[i*4+1] = v.y; xr[i*4+2] = v.z; xr[i*4+3] = v.w;
    }
#pragma unroll
    for (int t = 0; t < 4; ++t) {
      const int feat = t * 16 + c;
      const int fc   = feat < 50 ? feat : 0;
      float acc = bdown[fc];
#pragma unroll
      for (int k = 0; k < 24; ++k) acc = fmaf(xr[k], Wdown[k * 50 + fc], acc);
      o_m[t][g] = (feat < 50) ? acc : 0.f;
      stage[wave][4 * q + g][t * 16 + c] = o_m[t][g];
    }
  }

  // ---- diffusion coefficient per row (lane role: row=c, part=q) ----
  {
    float ov[50];
#pragma unroll
    for (int i = 0; i < 12; ++i) {
      float4 v = *(const float4*)&stage[wave][c][i * 4];
      ov[i*4+0] = v.x; ov[i*4+1] = v.y; ov[i*4+2] = v.z; ov[i*4+3] = v.w;
    }
    ov[48] = stage[wave][c][48]; ov[49] = stage[wave][c][49];
    float h = (q == 0) ? bd2[0] : 0.f;
    for (int m = q * 25; m < q * 25 + 25; ++m) {
      float a = bd1[m];
#pragma unroll
      for (int k = 0; k < 50; ++k) a = fmaf(ov[k], Wd1[k * 100 + m], a);
      h = fmaf(fmaxf(a, 0.f), Wd2[m], h);
    }
    h += __shfl_xor(h, 16);
    h += __shfl_xor(h, 32);
    float coef = 1.25f / (1.f + expf(-h));
    if (lane < 16) coefs[wave][lane] = coef;
  }
  float cf[4];
#pragma unroll
  for (int g = 0; g < 4; ++g) cf[g] = coefs[wave][4 * q + g];

  // noise counter base: counter = (wbase+4q+g)*50 + t*16 + c
  const unsigned nbase = (unsigned)(wbase + 4 * q) * 50u + (unsigned)c;

  // ---- 64 Euler-Maruyama steps (no barriers: wave-private staging) ----
  for (int s = 0; s < NSTEPS; ++s) {
    const unsigned k1 = KEYTAB.a[s];
    const unsigned k2 = KEYTAB.b[s];

    // A-frags from stage: lane reads row m=c, k = h*32 + q*8 + 0..7 (f32->bf16)
    FragU Af[2];
#pragma unroll
    for (int h = 0; h < 2; ++h) {
      float4 fa = *(const float4*)&stage[wave][c][h * 32 + q * 8];
      float4 fb = *(const float4*)&stage[wave][c][h * 32 + q * 8 + 4];
      Af[h].u[0] = packbf(fa.x, fa.y);
      Af[h].u[1] = packbf(fa.z, fa.w);
      Af[h].u[2] = packbf(fb.x, fb.y);
      Af[h].u[3] = packbf(fb.z, fb.w);
    }
    // drift matmul on the MFMA pipe: D[t] = o @ Wdrift + b  (bf16 in, f32 acc)
    f32x4 acc[4];
#pragma unroll
    for (int t = 0; t < 4; ++t) {
      acc[t] = __builtin_amdgcn_mfma_f32_16x16x32_bf16(Af[0].v, Bf[t][0].v, Cb[t], 0, 0, 0);
      acc[t] = __builtin_amdgcn_mfma_f32_16x16x32_bf16(Af[1].v, Bf[t][1].v, acc[t], 0, 0, 0);
    }
    // noise draws (VALU, overlaps MFMA): zc[t][g] = coef * N(0,1)
    float zc[4][4];
#pragma unroll
    for (int t = 0; t < 4; ++t) {
#pragma unroll
      for (int g = 0; g < 4; ++g) {
        unsigned bits = threefry_xor(k1, k2, nbase + (unsigned)(g * 50 + t * 16));
        zc[t][g] = cf[g] * gauss_from_bits(bits);
      }
    }
    // combine + write-back
#pragma unroll
    for (int t = 0; t < 4; ++t) {
#pragma unroll
      for (int g = 0; g < 4; ++g) {
        float on = fmaf(fmaxf(acc[t][g], 0.f), DT, o_m[t][g] + zc[t][g]);
        o_m[t][g] = on;
        stage[wave][4 * q + g][t * 16 + c] = on;
      }
    }
  }

  // ---- head: mu/sigma per row, reduce over the 16 c-lanes ----
  {
    float w0[4], w1[4];
#pragma unroll
    for (int t = 0; t < 4; ++t) {
      const int feat = t * 16 + c;
      const int fc   = feat < 50 ? feat : 0;
      const bool v   = feat < 50;
      w0[t] = v ? Wfc[fc * 2 + 0] : 0.f;
      w1[t] = v ? Wfc[fc * 2 + 1] : 0.f;
    }
    float mu[4], sv[4];
#pragma unroll
    for (int g = 0; g < 4; ++g) {
      float m = 0.f, sg = 0.f;
#pragma unroll
      for (int t = 0; t < 4; ++t) {
        float rv = fmaxf(o_m[t][g], 0.f);
        m  = fmaf(rv, w0[t], m);
        sg = fmaf(rv, w1[t], sg);
      }
      mu[g] = m; sv[g] = sg;
    }
#pragma unroll
    for (int st = 1; st < 16; st <<= 1) {
#pragma unroll
      for (int g = 0; g < 4; ++g) {
        mu[g] += __shfl_xor(mu[g], st);
        sv[g] += __shfl_xor(sv[g], st);
      }
    }
    if (c == 0) {
      const float b0 = bfc[0], b1 = bfc[1];
#pragma unroll
      for (int g = 0; g < 4; ++g) {
        const int r = wbase + 4 * q + g;
        out[r]          = mu[g] + b0;
        out[N_ROWS + r] = softplusf(sv[g] + b1) + 0.001f;
      }
    }
  }
}

extern "C" void kernel_launch(void* const* d_in, const int* in_sizes, int n_in,
                              void* d_out, int out_size, void* d_ws, size_t ws_size,
                              hipStream_t stream) {
  const float* x      = (const float*)d_in[0];
  const float* Wdown  = (const float*)d_in[1];
  const float* bdown  = (const float*)d_in[2];
  const float* Wdrift = (const float*)d_in[3];
  const float* bdrift = (const float*)d_in[4];
  const float* Wd1    = (const float*)d_in[5];
  const float* bd1    = (const float*)d_in[6];
  const float* Wd2    = (const float*)d_in[7];
  const float* bd2    = (const float*)d_in[8];
  const float* Wfc    = (const float*)d_in[9];
  const float* bfc    = (const float*)d_in[10];
  float* out = (float*)d_out;

  dim3 grid(N_ROWS / (RPW * WPB)), block(BLOCK);
  hipLaunchKernelGGL(sde_fused, grid, block, 0, stream,
                     x, Wdown, bdown, Wdrift, bdrift, Wd1, bd1, Wd2, bd2, Wfc, bfc, out);
}

// Round 6
// 8852.190 us; speedup vs baseline: 2.2108x; 1.2681x over previous
//
#include <hip/hip_runtime.h>
#include <hip/hip_bf16.h>

#define N_ROWS  1048576      // B*L = 2048*512
#define NSTEPS  64
#define DT      0.0625f      // 4/64
#define BLOCK   256          // 4 waves; each wave owns 16 rows
#define WPB     4
#define RPW     16
#define SROW    68           // stage row stride in floats (64 + 4 pad)
#define NROWSTR 52           // nbuf row stride in floats (50 + 2 pad)

typedef __attribute__((ext_vector_type(8))) short bfrag8;   // 8 bf16 (4 VGPRs)
typedef __attribute__((ext_vector_type(4))) float f32x4;    // MFMA C/D

union FragU { bfrag8 v; unsigned u[4]; };

// ---------- compile-time threefry for the 64 per-step folded keys ----------
constexpr unsigned rotl_c(unsigned x, int r) { return (x << r) | (x >> (32 - r)); }
struct KeyTab { unsigned a[NSTEPS]; unsigned b[NSTEPS]; };
constexpr KeyTab make_keytab() {
  KeyTab t{};
  for (int i = 0; i < NSTEPS; ++i) {
    const int R0[4] = {13, 15, 26, 6};
    const int R1[4] = {17, 29, 16, 24};
    unsigned k1 = 0u, k2 = 42u;
    unsigned ks[3] = {k1, k2, k1 ^ k2 ^ 0x1BD11BDAu};
    unsigned x0 = 0u + ks[0];
    unsigned x1 = (unsigned)i + ks[1];
    for (int g = 0; g < 5; ++g) {
      const int* R = (g % 2 == 0) ? R0 : R1;
      for (int qq = 0; qq < 4; ++qq) { x0 += x1; x1 = rotl_c(x1, R[qq]); x1 ^= x0; }
      x0 += ks[(g + 1) % 3];
      x1 += ks[(g + 2) % 3] + (unsigned)(g + 1);
    }
    t.a[i] = x0; t.b[i] = x1;
  }
  return t;
}
__constant__ KeyTab KEYTAB = make_keytab();

// ---------- device threefry2x32 (EXACT, bit-verified in R3) ----------
#define TF_ROUND(x0, x1, r) { x0 += x1; x1 = (x1 << (r)) | (x1 >> (32 - (r))); x1 ^= x0; }
__device__ __forceinline__ unsigned threefry_xor(unsigned k1, unsigned k2, unsigned c1) {
  unsigned ks2 = k1 ^ k2 ^ 0x1BD11BDAu;
  unsigned x0 = k1;          // c0 = 0
  unsigned x1 = c1 + k2;
  TF_ROUND(x0, x1, 13) TF_ROUND(x0, x1, 15) TF_ROUND(x0, x1, 26) TF_ROUND(x0, x1, 6)
  x0 += k2;  x1 += ks2 + 1u;
  TF_ROUND(x0, x1, 17) TF_ROUND(x0, x1, 29) TF_ROUND(x0, x1, 16) TF_ROUND(x0, x1, 24)
  x0 += ks2; x1 += k1 + 2u;
  TF_ROUND(x0, x1, 13) TF_ROUND(x0, x1, 15) TF_ROUND(x0, x1, 26) TF_ROUND(x0, x1, 6)
  x0 += k1;  x1 += k2 + 3u;
  TF_ROUND(x0, x1, 17) TF_ROUND(x0, x1, 29) TF_ROUND(x0, x1, 16) TF_ROUND(x0, x1, 24)
  x0 += k2;  x1 += ks2 + 4u;
  TF_ROUND(x0, x1, 13) TF_ROUND(x0, x1, 15) TF_ROUND(x0, x1, 26) TF_ROUND(x0, x1, 6)
  x0 += ks2; x1 += k1 + 5u;
  return x0 ^ x1;
}

// ---------- bits -> N(0,1): exact uniform map, fast log, branchy-tail erfinv ----------
// coefficients pre-multiplied by sqrt(2); tail branch (w>=5) hit by 0.34% of lanes
__device__ __forceinline__ float gauss_from_bits(unsigned bits) {
  float f = __uint_as_float((bits >> 9) | 0x3f800000u) - 1.0f;
  float u = fmaf(f, 2.0f, -0x1.fffffep-1f);   // [-0.99999994, 1)
  float w = -__logf(fmaf(-u, u, 1.0f));       // -ln(1 - u^2)
  float p;
  if (__builtin_expect(w < 5.0f, 1)) {
    float wm = w - 2.5f;
    p = 3.97402802e-08f;
    p = fmaf(p, wm, 4.85466e-07f);
    p = fmaf(p, wm, -4.98282e-06f);
    p = fmaf(p, wm, -6.21053e-06f);
    p = fmaf(p, wm, 3.09122e-04f);
    p = fmaf(p, wm, -1.77303338e-03f);
    p = fmaf(p, wm, -5.90813529e-03f);
    p = fmaf(p, wm, 3.48803145e-01f);
    p = fmaf(p, wm, 2.12331534e+00f);
  } else {
    float ws = __builtin_amdgcn_sqrtf(w) - 3.0f;
    p = -2.83146976e-04f;
    p = fmaf(p, ws, 1.42765612e-04f);
    p = fmaf(p, ws, 1.90826526e-03f);
    p = fmaf(p, ws, -5.19504700e-03f);
    p = fmaf(p, ws, 8.11689600e-03f);
    p = fmaf(p, ws, -1.07798700e-02f);
    p = fmaf(p, ws, 1.33487100e-02f);
    p = fmaf(p, ws, 1.41658100e+00f);
    p = fmaf(p, ws, 4.00643426e+00f);
  }
  return p * u;                                // = sqrt(2)*erfinv(u)
}

__device__ __forceinline__ float softplusf(float v) {
  return fmaxf(v, 0.f) + log1pf(expf(-fabsf(v)));
}

__device__ __forceinline__ unsigned packbf(float lo, float hi) {
  __hip_bfloat162 h = __float22bfloat162_rn(make_float2(lo, hi));  // .x = low half
  unsigned r; __builtin_memcpy(&r, &h, 4); return r;
}

// ---------- fused SDE-net forward; one wave = 16 rows, MFMA drift ----------
// launch_bounds(256,3): VGPR budget 170 -- fits the ~130 live regs, NO spills
__global__ void __launch_bounds__(BLOCK, 3) sde_fused(
    const float* __restrict__ x,
    const float* __restrict__ Wdown,  const float* __restrict__ bdown,
    const float* __restrict__ Wdrift, const float* __restrict__ bdrift,
    const float* __restrict__ Wd1,    const float* __restrict__ bd1,
    const float* __restrict__ Wd2,    const float* __restrict__ bd2,
    const float* __restrict__ Wfc,    const float* __restrict__ bfc,
    float* __restrict__ out) {
  // wave-private buffers (no barriers anywhere in the step loop)
  __shared__ __align__(16) float stage[WPB][RPW][SROW];   // o-state, f32
  __shared__ float nbuf[WPB][RPW][NROWSTR];               // this step's coef*noise
  __shared__ float coefs[WPB][RPW];

  const int tid  = threadIdx.x;
  const int wave = tid >> 6;
  const int lane = tid & 63;
  const int q    = lane >> 4;       // quad 0..3
  const int c    = lane & 15;       // col-in-tile / A-row
  const int wbase = (blockIdx.x * WPB + wave) * RPW;

  // ---- loop-invariant B-fragments of W_drift (padded 64x64, bf16) ----
  FragU Bf[4][2];
#pragma unroll
  for (int t = 0; t < 4; ++t) {
    const int nn = t * 16 + c;
    const bool nv = nn < 50;
#pragma unroll
    for (int h = 0; h < 2; ++h) {
#pragma unroll
      for (int j2 = 0; j2 < 4; ++j2) {
        const int k0 = h * 32 + q * 8 + j2 * 2;
        float v0 = (nv && k0 < 50)     ? Wdrift[k0 * 50 + nn]       : 0.f;
        float v1 = (nv && (k0+1) < 50) ? Wdrift[(k0 + 1) * 50 + nn] : 0.f;
        Bf[t][h].u[j2] = packbf(v0, v1);
      }
    }
  }
  // C-init = b_drift broadcast per tile (0 on pad cols)
  f32x4 Cb[4];
#pragma unroll
  for (int t = 0; t < 4; ++t) {
    const int nn = t * 16 + c;
    float b = (nn < 50) ? bdrift[nn] : 0.f;
    Cb[t] = (f32x4){b, b, b, b};
  }

  // ---- down-projection into master registers (D-layout) + stage ----
  float o_m[4][4];   // o_m[t][g]: row = 4q+g, feat = t*16+c
#pragma unroll
  for (int g = 0; g < 4; ++g) {
    const float* xrp = x + (size_t)(wbase + 4 * q + g) * 24;
    float xr[24];
#pragma unroll
    for (int i = 0; i < 6; ++i) {
      float4 v = ((const float4*)xrp)[i];
      xr[i*4+0] = v.x; xr[i*4+1] = v.y; xr[i*4+2] = v.z; xr[i*4+3] = v.w;
    }
#pragma unroll
    for (int t = 0; t < 4; ++t) {
      const int feat = t * 16 + c;
      const int fc   = feat < 50 ? feat : 0;
      float acc = bdown[fc];
#pragma unroll
      for (int k = 0; k < 24; ++k) acc = fmaf(xr[k], Wdown[k * 50 + fc], acc);
      o_m[t][g] = (feat < 50) ? acc : 0.f;
      stage[wave][4 * q + g][t * 16 + c] = o_m[t][g];
    }
  }

  // ---- diffusion coefficient per row (lane role: row=c, part=q) ----
  {
    float ov[50];
#pragma unroll
    for (int i = 0; i < 12; ++i) {
      float4 v = *(const float4*)&stage[wave][c][i * 4];
      ov[i*4+0] = v.x; ov[i*4+1] = v.y; ov[i*4+2] = v.z; ov[i*4+3] = v.w;
    }
    ov[48] = stage[wave][c][48]; ov[49] = stage[wave][c][49];
    float h = (q == 0) ? bd2[0] : 0.f;
    for (int m = q * 25; m < q * 25 + 25; ++m) {
      float a = bd1[m];
#pragma unroll
      for (int k = 0; k < 50; ++k) a = fmaf(ov[k], Wd1[k * 100 + m], a);
      h = fmaf(fmaxf(a, 0.f), Wd2[m], h);
    }
    h += __shfl_xor(h, 16);
    h += __shfl_xor(h, 32);
    float coef = 1.25f / (1.f + expf(-h));
    if (lane < 16) coefs[wave][lane] = coef;
  }

  // ---- 64 Euler-Maruyama steps (wave-private: zero barriers) ----
  const unsigned cbase = (unsigned)wbase * 50u;
  for (int s = 0; s < NSTEPS; ++s) {
    const unsigned k1 = KEYTAB.a[s];
    const unsigned k2 = KEYTAB.b[s];

    // Phase 1: draw exactly the 800 needed noise values (flat counters),
    // route to (row, feat) slots via wave-private nbuf. idx = lane + 64k.
#pragma unroll
    for (int k = 0; k < 13; ++k) {
      const int idx = lane + (k << 6);
      if (k < 12 || idx < 800) {                 // last iter: half-masked
        unsigned bits = threefry_xor(k1, k2, cbase + (unsigned)idx);
        float z = gauss_from_bits(bits);
        const int row  = (idx * 41) >> 11;       // exact idx/50 for idx<800
        const int feat = idx - row * 50;
        nbuf[wave][row][feat] = coefs[wave][row] * z;
      }
    }

    // Phase 2: A-frags from stage (f32 -> bf16); lane = row c, k = h*32+q*8+j
    FragU Af[2];
#pragma unroll
    for (int h = 0; h < 2; ++h) {
      float4 fa = *(const float4*)&stage[wave][c][h * 32 + q * 8];
      float4 fb = *(const float4*)&stage[wave][c][h * 32 + q * 8 + 4];
      Af[h].u[0] = packbf(fa.x, fa.y);
      Af[h].u[1] = packbf(fa.z, fa.w);
      Af[h].u[2] = packbf(fb.x, fb.y);
      Af[h].u[3] = packbf(fb.z, fb.w);
    }

    // Phase 3: drift matmul on the MFMA pipe
    f32x4 acc[4];
#pragma unroll
    for (int t = 0; t < 4; ++t) {
      acc[t] = __builtin_amdgcn_mfma_f32_16x16x32_bf16(Af[0].v, Bf[t][0].v, Cb[t], 0, 0, 0);
      acc[t] = __builtin_amdgcn_mfma_f32_16x16x32_bf16(Af[1].v, Bf[t][1].v, acc[t], 0, 0, 0);
    }

    // Phase 4: combine + write-back (pads stay exactly 0: no noise, zero B rows)
#pragma unroll
    for (int t = 0; t < 4; ++t) {
      const int feat = t * 16 + c;               // t<3: compile-time valid
#pragma unroll
      for (int g = 0; g < 4; ++g) {
        float nz = (feat < 50) ? nbuf[wave][4 * q + g][feat] : 0.f;
        float on = fmaf(fmaxf(acc[t][g], 0.f), DT, o_m[t][g] + nz);
        o_m[t][g] = on;
        stage[wave][4 * q + g][feat] = on;
      }
    }
  }

  // ---- head: mu/sigma per row, reduce over the 16 c-lanes ----
  {
    float w0[4], w1[4];
#pragma unroll
    for (int t = 0; t < 4; ++t) {
      const int feat = t * 16 + c;
      const int fc   = feat < 50 ? feat : 0;
      const bool v   = feat < 50;
      w0[t] = v ? Wfc[fc * 2 + 0] : 0.f;
      w1[t] = v ? Wfc[fc * 2 + 1] : 0.f;
    }
    float mu[4], sv[4];
#pragma unroll
    for (int g = 0; g < 4; ++g) {
      float m = 0.f, sg = 0.f;
#pragma unroll
      for (int t = 0; t < 4; ++t) {
        float rv = fmaxf(o_m[t][g], 0.f);
        m  = fmaf(rv, w0[t], m);
        sg = fmaf(rv, w1[t], sg);
      }
      mu[g] = m; sv[g] = sg;
    }
#pragma unroll
    for (int st = 1; st < 16; st <<= 1) {
#pragma unroll
      for (int g = 0; g < 4; ++g) {
        mu[g] += __shfl_xor(mu[g], st);
        sv[g] += __shfl_xor(sv[g], st);
      }
    }
    if (c == 0) {
      const float b0 = bfc[0], b1 = bfc[1];
#pragma unroll
      for (int g = 0; g < 4; ++g) {
        const int r = wbase + 4 * q + g;
        out[r]          = mu[g] + b0;
        out[N_ROWS + r] = softplusf(sv[g] + b1) + 0.001f;
      }
    }
  }
}

extern "C" void kernel_launch(void* const* d_in, const int* in_sizes, int n_in,
                              void* d_out, int out_size, void* d_ws, size_t ws_size,
                              hipStream_t stream) {
  const float* x      = (const float*)d_in[0];
  const float* Wdown  = (const float*)d_in[1];
  const float* bdown  = (const float*)d_in[2];
  const float* Wdrift = (const float*)d_in[3];
  const float* bdrift = (const float*)d_in[4];
  const float* Wd1    = (const float*)d_in[5];
  const float* bd1    = (const float*)d_in[6];
  const float* Wd2    = (const float*)d_in[7];
  const float* bd2    = (const float*)d_in[8];
  const float* Wfc    = (const float*)d_in[9];
  const float* bfc    = (const float*)d_in[10];
  float* out = (float*)d_out;

  dim3 grid(N_ROWS / (RPW * WPB)), block(BLOCK);
  hipLaunchKernelGGL(sde_fused, grid, block, 0, stream,
                     x, Wdown, bdown, Wdrift, bdrift, Wd1, bd1, Wd2, bd2, Wfc, bfc, out);
}